// Round 1
// baseline (141.645 us; speedup 1.0000x reference)
//
#include <hip/hip_runtime.h>

// NCC2D fused: 5 box-sums (9x9, zero-pad) + cc + global mean, single pass.
// Design C: thread owns 2 columns; horizontal sums from global halo loads
// (L1-absorbed overlap); vertical 9-row running window in a register ring
// with static indices (inner loop unrolled by 9; 18 input rows = 2*9).
// R1 change: SH 28->10 (NROWS 36->18). Grid 608 -> 1664 blocks (2.4 -> 6.5
// blocks/CU) to attack latency-bound execution; halo re-read 1.29x -> 1.8x.
// d_ws: 1664 block partials (float). Kernel 2 reduces in double -> -mean.

#define BATCH   32
#define IMH     512
#define IMW     512
#define SH      10          // output rows per block
#define NSTRIP  52          // ceil(512/10); 52*10 = 520 (tail masked)
#define NROWS   18          // SH + 8 halo rows; multiple of 9
#define NPART   (BATCH * NSTRIP)

__global__ __launch_bounds__(256) void ncc_main(const float* __restrict__ I,
                                                const float* __restrict__ J,
                                                float* __restrict__ partial) {
    const int t  = threadIdx.x;
    const int s  = blockIdx.x;   // strip
    const int b  = blockIdx.y;   // image
    const int r0 = s * SH;       // first output row of strip
    const float inv81 = 1.0f / 81.0f;

    const float* Ib = I + (size_t)b * IMH * IMW;
    const float* Jb = J + (size_t)b * IMH * IMW;

    const int cbase = 2 * t - 4; // leftmost halo column for this thread

    // ring[j][q]: horizontal sums H of the last 9 input rows, per quantity
    // q: 0=I 1=J 2=II 3=JJ 4=IJ ; .x = col 2t, .y = col 2t+1
    float2 ring[9][5];
#pragma unroll
    for (int j = 0; j < 9; ++j)
#pragma unroll
        for (int q = 0; q < 5; ++q) ring[j][q] = make_float2(0.f, 0.f);

    float2 V[5];
#pragma unroll
    for (int q = 0; q < 5; ++q) V[q] = make_float2(0.f, 0.f);

    float2 acc = make_float2(0.f, 0.f);

#pragma unroll 1
    for (int g = 0; g < NROWS / 9; ++g) {
#pragma unroll
        for (int j = 0; j < 9; ++j) {
            const int i  = g * 9 + j;     // iteration 0..NROWS-1
            const int ri = r0 - 4 + i;    // input row (may be OOB -> zeros)

            float vI[10], vJ[10];
            if ((unsigned)ri < (unsigned)IMH) {
                const float* rowI = Ib + (size_t)ri * IMW;
                const float* rowJ = Jb + (size_t)ri * IMW;
#pragma unroll
                for (int k = 0; k < 5; ++k) {
                    const int ck = cbase + 2 * k;   // even; pair never straddles edge
                    if ((unsigned)ck < (unsigned)IMW) {
                        float2 iv = *(const float2*)(rowI + ck);
                        float2 jv = *(const float2*)(rowJ + ck);
                        vI[2 * k] = iv.x; vI[2 * k + 1] = iv.y;
                        vJ[2 * k] = jv.x; vJ[2 * k + 1] = jv.y;
                    } else {
                        vI[2 * k] = 0.f; vI[2 * k + 1] = 0.f;
                        vJ[2 * k] = 0.f; vJ[2 * k + 1] = 0.f;
                    }
                }
            } else {
#pragma unroll
                for (int m = 0; m < 10; ++m) { vI[m] = 0.f; vJ[m] = 0.f; }
            }

            // horizontal 9-window sums for the two owned columns
            float sI = 0.f, sJ = 0.f, sII = 0.f, sJJ = 0.f, sIJ = 0.f;
#pragma unroll
            for (int m = 0; m < 9; ++m) {
                sI  += vI[m];
                sJ  += vJ[m];
                sII += vI[m] * vI[m];
                sJJ += vJ[m] * vJ[m];
                sIJ += vI[m] * vJ[m];
            }
            const float i0 = vI[0], j0 = vJ[0], i9 = vI[9], j9 = vJ[9];
            float2 Hn[5];
            Hn[0] = make_float2(sI,  sI  + i9      - i0);
            Hn[1] = make_float2(sJ,  sJ  + j9      - j0);
            Hn[2] = make_float2(sII, sII + i9 * i9 - i0 * i0);
            Hn[3] = make_float2(sJJ, sJJ + j9 * j9 - j0 * j0);
            Hn[4] = make_float2(sIJ, sIJ + i9 * j9 - i0 * j0);

            // vertical running window: V = sum of last 9 H rows
#pragma unroll
            for (int q = 0; q < 5; ++q) {
                const float2 old = ring[j][q];
                ring[j][q] = Hn[q];
                V[q].x += Hn[q].x - old.x;
                V[q].y += Hn[q].y - old.y;
            }

            // emit output row r = ri - 4 once 9 rows accumulated
            if (i >= 8) {
                const int r = r0 + i - 8;
                if (r < IMH) {
                    {
                        const float aI = V[0].x, aJ = V[1].x;
                        const float cross = V[4].x - aI * aJ * inv81;
                        const float iv    = V[2].x - aI * aI * inv81;
                        const float jv    = V[3].x - aJ * aJ * inv81;
                        acc.x += cross * cross *
                                 __builtin_amdgcn_rcpf(iv * jv + 1e-5f);
                    }
                    {
                        const float aI = V[0].y, aJ = V[1].y;
                        const float cross = V[4].y - aI * aJ * inv81;
                        const float iv    = V[2].y - aI * aI * inv81;
                        const float jv    = V[3].y - aJ * aJ * inv81;
                        acc.y += cross * cross *
                                 __builtin_amdgcn_rcpf(iv * jv + 1e-5f);
                    }
                }
            }
        }
    }

    // block reduction: wave shuffle, then LDS across the 4 waves
    float sum = acc.x + acc.y;
#pragma unroll
    for (int off = 32; off > 0; off >>= 1) sum += __shfl_down(sum, off, 64);

    __shared__ float wsum[4];
    if ((t & 63) == 0) wsum[t >> 6] = sum;
    __syncthreads();
    if (t == 0) {
        partial[(size_t)b * NSTRIP + s] = wsum[0] + wsum[1] + wsum[2] + wsum[3];
    }
}

__global__ __launch_bounds__(256) void ncc_reduce(const float* __restrict__ partial,
                                                  float* __restrict__ out) {
    const int t = threadIdx.x;
    double ssum = 0.0;
    for (int idx = t; idx < NPART; idx += 256) ssum += (double)partial[idx];
#pragma unroll
    for (int off = 32; off > 0; off >>= 1) ssum += __shfl_down(ssum, off, 64);

    __shared__ double wsum[4];
    if ((t & 63) == 0) wsum[t >> 6] = ssum;
    __syncthreads();
    if (t == 0) {
        const double total = wsum[0] + wsum[1] + wsum[2] + wsum[3];
        out[0] = (float)(-total / 8388608.0);  // -mean over 32*512*512
    }
}

extern "C" void kernel_launch(void* const* d_in, const int* in_sizes, int n_in,
                              void* d_out, int out_size, void* d_ws, size_t ws_size,
                              hipStream_t stream) {
    const float* I = (const float*)d_in[0];  // y_true
    const float* J = (const float*)d_in[1];  // y_pred
    float* partial = (float*)d_ws;           // NPART floats
    float* out     = (float*)d_out;

    dim3 grid(NSTRIP, BATCH);
    ncc_main<<<grid, 256, 0, stream>>>(I, J, partial);
    ncc_reduce<<<1, 256, 0, stream>>>(partial, out);
}